// Round 10
// baseline (309.148 us; speedup 1.0000x reference)
//
#include <hip/hip_runtime.h>

#define B_ROWS 8192
#define IN_F 512
#define OUT_F 1024
#define K_TOT 1536

#define BM 64
#define BN 64
#define BK 64
#define NITER (K_TOT / BK)          // 24

#define A4_COUNT (B_ROWS * (K_TOT / 4))       // 3,145,728 float4 cast tasks
#define W4_COUNT (OUT_F  * (K_TOT / 4))       //   393,216
#define CAST_BLOCKS ((A4_COUNT + W4_COUNT) / 1024)   // 3456 (4 tasks/thread)
#define P_BLOCKS ((B_ROWS * OUT_F / 4) / 1024)       // 2048 pointwise blocks
#define PW_BLOCKS (CAST_BLOCKS + P_BLOCKS)           // 5504
#define GEMM_BLOCKS ((B_ROWS / BM) * (OUT_F / BN))   // 2048

typedef short bfrag __attribute__((ext_vector_type(8)));   // 8 bf16 = 4 VGPRs
typedef float f4    __attribute__((ext_vector_type(4)));

// round-to-nearest-even fp32 -> bf16, packed pairwise into a dword
__device__ __forceinline__ unsigned int pack2bf(float a, float b) {
    unsigned int ua = __float_as_uint(a);
    unsigned int ub = __float_as_uint(b);
    ua = (ua + 0x7fffu + ((ua >> 16) & 1u)) >> 16;
    ub = (ub + 0x7fffu + ((ub >> 16) & 1u)) & 0xffff0000u;
    return ua | ub;
}

// ------- pass 1: block-homogeneous streaming (cast A/W + pointwise) --------
// Blocks 0..3455: fp32->bf16 cast of A=[spikes|z] and W=[Wi|Wr], MLP x4
//   (measured ~4.7+ TB/s as precast_aw in R6/R9).
// Blocks 3456..5503: GEMM-independent output planes z/v/b (planes 0,1,3),
//   MLP x4, nontemporal stores (96 MB never re-read).
// Rationale (R9 post-mortem): R4 proved the SLIM gemm runs ~48 us; R4's
// pointwise pass was the slow piece (1 task/thread, 2.5 TB/s latency-bound).
// This kernel applies the proven MLP x4 fix to that pass. Block-level
// specialization -> no per-thread divergence, no LDS, full occupancy.
__global__ __launch_bounds__(256) void precast_pw(
    const float* __restrict__ spikes, const float* __restrict__ zin,
    const float* __restrict__ Wi,     const float* __restrict__ Wr,
    const float* __restrict__ vin,    const float* __restrict__ iin,
    const float* __restrict__ bin,
    unsigned short* __restrict__ Abf, unsigned short* __restrict__ Wbf,
    float* __restrict__ out)
{
    const int bid = blockIdx.x;
    if (bid < CAST_BLOCKS) {
        const int base = bid * 1024 + threadIdx.x;
        const float4* src[4];
        #pragma unroll
        for (int k = 0; k < 4; ++k) {
            const int idx = base + k * 256;
            if (idx < A4_COUNT) {
                const int row = idx / 384, c4 = idx - row * 384;
                src[k] = (const float4*)((c4 < 128)
                             ? spikes + (size_t)row * IN_F + c4 * 4
                             : zin    + (size_t)row * OUT_F + (c4 - 128) * 4);
            } else {
                const int w = idx - A4_COUNT;
                const int row = w / 384, c4 = w - row * 384;
                src[k] = (const float4*)((c4 < 128)
                             ? Wi + (size_t)row * IN_F + c4 * 4
                             : Wr + (size_t)row * OUT_F + (c4 - 128) * 4);
            }
        }
        float4 val[4];
        #pragma unroll
        for (int k = 0; k < 4; ++k) val[k] = *src[k];
        #pragma unroll
        for (int k = 0; k < 4; ++k) {
            const int idx = base + k * 256;
            unsigned short* dst = (idx < A4_COUNT)
                                      ? Abf + (size_t)idx * 4
                                      : Wbf + (size_t)(idx - A4_COUNT) * 4;
            uint2 pk = { pack2bf(val[k].x, val[k].y), pack2bf(val[k].z, val[k].w) };
            *(uint2*)dst = pk;   // re-read by gemm soon: keep cacheable
        }
    } else {
        const int pb = bid - CAST_BLOCKS;           // 0..2047
        const int base = pb * 1024 + threadIdx.x;   // f4 index into [B, OUT_F]
        const size_t PL = (size_t)B_ROWS * OUT_F;
        const f4* v4 = (const f4*)vin;
        const f4* i4 = (const f4*)iin;
        const f4* b4 = (const f4*)bin;
        f4 vv[4], ii[4], bb[4];
        #pragma unroll
        for (int k = 0; k < 4; ++k) vv[k] = v4[base + k * 256];
        #pragma unroll
        for (int k = 0; k < 4; ++k) ii[k] = i4[base + k * 256];
        #pragma unroll
        for (int k = 0; k < 4; ++k) bb[k] = b4[base + k * 256];
        #pragma unroll
        for (int k = 0; k < 4; ++k) {
            f4 z, vn, bn;
            #pragma unroll
            for (int c = 0; c < 4; ++c) {
                const float v_dec = vv[k][c] + 0.1f * (ii[k][c] - vv[k][c]);
                const float b_dec = bb[k][c] + 1.25e-06f * (1.0f - bb[k][c]);
                const float zz = (v_dec - b_dec > 0.0f) ? 1.0f : 0.0f;
                z[c]  = zz;
                vn[c] = (1.0f - zz) * v_dec;
                bn[c] = b_dec + zz * 0.00225f;
            }
            const int j = base + k * 256;
            __builtin_nontemporal_store(z,  (f4*)out + j);               // plane 0
            __builtin_nontemporal_store(vn, (f4*)(out + PL) + j);        // plane 1
            __builtin_nontemporal_store(bn, (f4*)(out + 3 * PL) + j);    // plane 3
        }
    }
}

// ---------------- pass 2: slim bf16 GEMM + i-plane epilogue ----------------
// R4's measured-fast configuration (~48 us inferred: 308.5 total - 178 fixed
// - 83 streaming), verbatim: 64x64 tile, XOR-swizzled gload_lds (0 bank
// conflicts), T3 2-phase pipeline (stage(t+1) before compute, single
// __syncthreads per iter at the END), epilogue touches ONLY plane 2.
__global__ __launch_bounds__(256, 4) void lsnn_gemm(
    const unsigned short* __restrict__ Abf,   // [8192, 1536] bf16
    const unsigned short* __restrict__ Wbf,   // [1024, 1536] bf16
    const float* __restrict__ iin,
    float* __restrict__ out)                  // writes plane 2 only
{
    __shared__ unsigned short As[2][BM * BK];   // 2 x 8 KB
    __shared__ unsigned short Ws[2][BN * BK];   // 2 x 8 KB

    const int tid = threadIdx.x;
    const int bid = blockIdx.x;
    // bid&15 -> n-tile: XCD = bid%8 sees n-tiles {j, j+8} only -> 2 W slices
    // (2 x 192 KB) pinned per XCD L2 for the whole dispatch.
    const int n0 = (bid & 15) * BN;
    const int m0 = (bid >> 4) * BM;

    const int lane = tid & 63;
    const int wave = tid >> 6;
    const int wm = (wave >> 1) * 32;   // 2x2 wave grid over 64x64
    const int wn = (wave & 1) * 32;
    const int lr = lane & 15;
    const int lq = lane >> 4;

    f4 acc[2][2];
    #pragma unroll
    for (int a = 0; a < 2; ++a)
        #pragma unroll
        for (int b = 0; b < 2; ++b)
            acc[a][b] = (f4)0.0f;

    const unsigned short* Ab = Abf + (size_t)m0 * K_TOT;
    const unsigned short* Wb = Wbf + (size_t)n0 * K_TOT;

    // Staging geometry: 512 chunks/tile (64 rows x 8), XOR swizzle
    // slot = c ^ (r&7) (verified 0-conflict). 8 rows x 8 lanes per inst
    // -> 8x128B coalesced global segments.
    int rr[2], cc_[2], jj[2];
    #pragma unroll
    for (int p = 0; p < 2; ++p) {
        const int q = p * 256 + wave * 64 + lane;   // chunk 0..511
        rr[p] = q >> 3;
        cc_[p] = (q & 7) ^ (rr[p] & 7);
        jj[p] = p * 256 + wave * 64;
    }

    auto stage = [&](int buf, int kt) {
        #pragma unroll
        for (int p = 0; p < 2; ++p)
            __builtin_amdgcn_global_load_lds(
                (const __attribute__((address_space(1))) void*)(Ab + (size_t)rr[p] * K_TOT + kt + cc_[p] * 8),
                (__attribute__((address_space(3))) void*)(&As[buf][jj[p] * 8]),
                16, 0, 0);
        #pragma unroll
        for (int p = 0; p < 2; ++p)
            __builtin_amdgcn_global_load_lds(
                (const __attribute__((address_space(1))) void*)(Wb + (size_t)rr[p] * K_TOT + kt + cc_[p] * 8),
                (__attribute__((address_space(3))) void*)(&Ws[buf][jj[p] * 8]),
                16, 0, 0);
    };

    stage(0, 0);
    __syncthreads();

    int cur = 0;
    for (int it = 0; it < NITER; ++it) {
        if (it + 1 < NITER) stage(cur ^ 1, (it + 1) * BK);

        #pragma unroll
        for (int ks = 0; ks < 2; ++ks) {
            const int cc = ks * 4 + lq;
            bfrag af[2], wf[2];
            #pragma unroll
            for (int t = 0; t < 2; ++t) {
                const int row = wm + t * 16 + lr;
                af[t] = *(const bfrag*)&As[cur][row * BK + ((cc ^ (row & 7)) << 3)];
            }
            #pragma unroll
            for (int t = 0; t < 2; ++t) {
                const int row = wn + t * 16 + lr;
                wf[t] = *(const bfrag*)&Ws[cur][row * BK + ((cc ^ (row & 7)) << 3)];
            }
            #pragma unroll
            for (int tm = 0; tm < 2; ++tm)
                #pragma unroll
                for (int tn = 0; tn < 2; ++tn)
                    acc[tm][tn] = __builtin_amdgcn_mfma_f32_16x16x32_bf16(
                        af[tm], wf[tn], acc[tm][tn], 0, 0, 0);
        }

        __syncthreads();   // drains tile t+1 after compute (overlapped)
        cur ^= 1;
    }

    // Epilogue: GEMM-dependent plane only (i_new = i_decayed + acc).
    // i is L3-warm (streamed by pass 1). C/D mapping col = lane&15,
    // row = (lane>>4)*4 + reg (m89/m91).
    const size_t PL2 = 2 * (size_t)B_ROWS * OUT_F;
    #pragma unroll
    for (int tm = 0; tm < 2; ++tm) {
        #pragma unroll
        for (int tn = 0; tn < 2; ++tn) {
            #pragma unroll
            for (int r = 0; r < 4; ++r) {
                const int gm = m0 + wm + tm * 16 + lq * 4 + r;
                const int gn = n0 + wn + tn * 16 + lr;
                const size_t idx = (size_t)gm * OUT_F + gn;
                const float i = iin[idx];
                __builtin_nontemporal_store((i - 0.2f * i) + acc[tm][tn][r],
                                            &out[PL2 + idx]);
            }
        }
    }
}

extern "C" void kernel_launch(void* const* d_in, const int* in_sizes, int n_in,
                              void* d_out, int out_size, void* d_ws, size_t ws_size,
                              hipStream_t stream) {
    const float* spikes = (const float*)d_in[0];
    const float* z      = (const float*)d_in[1];
    const float* v      = (const float*)d_in[2];
    const float* i      = (const float*)d_in[3];
    const float* b      = (const float*)d_in[4];
    const float* Wi     = (const float*)d_in[5];
    const float* Wr     = (const float*)d_in[6];
    float* out = (float*)d_out;

    unsigned short* Abf = (unsigned short*)d_ws;                       // 25,165,824 B
    unsigned short* Wbf = Abf + (size_t)B_ROWS * K_TOT;                //  3,145,728 B

    precast_pw<<<PW_BLOCKS, 256, 0, stream>>>(
        spikes, z, Wi, Wr, v, i, b, Abf, Wbf, out);                    // 5504 blocks

    lsnn_gemm<<<GEMM_BLOCKS, 256, 0, stream>>>(Abf, Wbf, i, out);      // 2048 blocks
}

// Round 11
// 296.264 us; speedup vs baseline: 1.0435x; 1.0435x over previous
//
#include <hip/hip_runtime.h>

#define B_ROWS 8192
#define IN_F 512
#define OUT_F 1024
#define K_TOT 1536

#define BM 64
#define BN 64
#define BK 64
#define NITER (K_TOT / BK)          // 24

#define A4_COUNT (B_ROWS * (K_TOT / 4))       // 3,145,728 float4 tasks
#define W4_COUNT (OUT_F  * (K_TOT / 4))       //   393,216
#define CAST_BLOCKS ((A4_COUNT + W4_COUNT) / 1024)   // 3456 (4 tasks/thread)
#define GEMM_BLOCKS ((B_ROWS / BM) * (OUT_F / BN))   // 2048

typedef short bfrag __attribute__((ext_vector_type(8)));   // 8 bf16 = 4 VGPRs
typedef float f4    __attribute__((ext_vector_type(4)));

// round-to-nearest-even fp32 -> bf16, packed pairwise into a dword
__device__ __forceinline__ unsigned int pack2bf(float a, float b) {
    unsigned int ua = __float_as_uint(a);
    unsigned int ub = __float_as_uint(b);
    ua = (ua + 0x7fffu + ((ua >> 16) & 1u)) >> 16;
    ub = (ub + 0x7fffu + ((ub >> 16) & 1u)) & 0xffff0000u;
    return ua | ub;
}

// ---------------- pass 1: fp32 -> bf16 precast of A and W ------------------
// A_bf16[8192][1536] = [spikes | z], W_bf16[1024][1536] = [Wi | Wr].
// MLP x4 (4 float4 tasks/thread, stride 256) — ~15-18 us measured (R6/R9).
__global__ __launch_bounds__(256) void precast_aw(
    const float* __restrict__ spikes, const float* __restrict__ zin,
    const float* __restrict__ Wi,     const float* __restrict__ Wr,
    unsigned short* __restrict__ Abf, unsigned short* __restrict__ Wbf)
{
    const int base = blockIdx.x * 1024 + threadIdx.x;
    const float4* src[4];
    #pragma unroll
    for (int k = 0; k < 4; ++k) {
        const int idx = base + k * 256;
        if (idx < A4_COUNT) {
            const int row = idx / 384, c4 = idx - row * 384;
            src[k] = (const float4*)((c4 < 128)
                         ? spikes + (size_t)row * IN_F + c4 * 4
                         : zin    + (size_t)row * OUT_F + (c4 - 128) * 4);
        } else {
            const int w = idx - A4_COUNT;
            const int row = w / 384, c4 = w - row * 384;
            src[k] = (const float4*)((c4 < 128)
                         ? Wi + (size_t)row * IN_F + c4 * 4
                         : Wr + (size_t)row * OUT_F + (c4 - 128) * 4);
        }
    }
    float4 val[4];
    #pragma unroll
    for (int k = 0; k < 4; ++k) val[k] = *src[k];
    #pragma unroll
    for (int k = 0; k < 4; ++k) {
        const int idx = base + k * 256;
        unsigned short* dst = (idx < A4_COUNT)
                                  ? Abf + (size_t)idx * 4
                                  : Wbf + (size_t)(idx - A4_COUNT) * 4;
        uint2 pk = { pack2bf(val[k].x, val[k].y), pack2bf(val[k].z, val[k].w) };
        *(uint2*)dst = pk;
    }
}

// ---------------- pass 2: GEMM + in-block fused pointwise ------------------
// Exact R6 structure (best measured: fat gemm 101 us, total 297.2) with ONE
// change: a sched_barrier(0) after the 12 v/i/b prefetch loads. R6's
// VGPR=52 proved the compiler SANK the loads to the epilogue (T14 never
// happened). The side-effecting intrinsic blocks IR + MachineScheduler
// sinking WITHOUT forcing a waitcnt — the loads drain for free at the
// K-loop's first __syncthreads (shared with tile-0's vmcnt drain), and the
// data then sits in VGPRs so the end-of-kernel burst is pure VALU+stores.
// Everything else verbatim: 64x64 tile, XOR-swizzled gload_lds (0 bank
// conflicts), T3 2-phase pipeline, linear pointwise mapping, NT plane
// stores, plane-2 epilogue with L3-warm i re-read.
__global__ __launch_bounds__(256, 4) void lsnn_gemm(
    const unsigned short* __restrict__ Abf,   // [8192, 1536] bf16
    const unsigned short* __restrict__ Wbf,   // [1024, 1536] bf16
    const float* __restrict__ vin,
    const float* __restrict__ iin,
    const float* __restrict__ bin,
    float* __restrict__ out)                  // all 4 planes
{
    __shared__ unsigned short As[2][BM * BK];   // 2 x 8 KB
    __shared__ unsigned short Ws[2][BN * BK];   // 2 x 8 KB

    const int tid = threadIdx.x;
    const int bid = blockIdx.x;                 // 0..2047
    // bid&15 -> n-tile: XCD = bid%8 sees n-tiles {j, j+8} only -> 2 W slices
    // (2 x 192 KB) pinned per XCD L2 for the whole dispatch.
    const int n0 = (bid & 15) * BN;
    const int m0 = (bid >> 4) * BM;

    // ---- pointwise prefetch: 12 f4 loads, pinned BEFORE the K-loop ----
    const int pw = bid * 1024 + tid;            // f4 index into [B, OUT_F]
    const f4* v4 = (const f4*)vin;
    const f4* i4 = (const f4*)iin;
    const f4* b4 = (const f4*)bin;
    f4 vv[4], ii[4], bb[4];
    #pragma unroll
    for (int k = 0; k < 4; ++k) vv[k] = v4[pw + k * 256];
    #pragma unroll
    for (int k = 0; k < 4; ++k) ii[k] = i4[pw + k * 256];
    #pragma unroll
    for (int k = 0; k < 4; ++k) bb[k] = b4[pw + k * 256];
    __builtin_amdgcn_sched_barrier(0);   // forbid sinking the loads below here

    // ---- gemm geometry ----
    const int lane = tid & 63;
    const int wave = tid >> 6;
    const int wm = (wave >> 1) * 32;   // 2x2 wave grid over 64x64
    const int wn = (wave & 1) * 32;
    const int lr = lane & 15;
    const int lq = lane >> 4;

    f4 acc[2][2];
    #pragma unroll
    for (int a = 0; a < 2; ++a)
        #pragma unroll
        for (int b = 0; b < 2; ++b)
            acc[a][b] = (f4)0.0f;

    const unsigned short* Ab = Abf + (size_t)m0 * K_TOT;
    const unsigned short* Wb = Wbf + (size_t)n0 * K_TOT;

    // Staging geometry: 512 chunks/tile (64 rows x 8), XOR swizzle
    // slot = c ^ (r&7) (verified 0-conflict). 8 rows x 8 lanes per inst
    // -> 8x128B coalesced global segments.
    int rr[2], cc_[2], jj[2];
    #pragma unroll
    for (int p = 0; p < 2; ++p) {
        const int q = p * 256 + wave * 64 + lane;   // chunk 0..511
        rr[p] = q >> 3;
        cc_[p] = (q & 7) ^ (rr[p] & 7);
        jj[p] = p * 256 + wave * 64;
    }

    auto stage = [&](int buf, int kt) {
        #pragma unroll
        for (int p = 0; p < 2; ++p)
            __builtin_amdgcn_global_load_lds(
                (const __attribute__((address_space(1))) void*)(Ab + (size_t)rr[p] * K_TOT + kt + cc_[p] * 8),
                (__attribute__((address_space(3))) void*)(&As[buf][jj[p] * 8]),
                16, 0, 0);
        #pragma unroll
        for (int p = 0; p < 2; ++p)
            __builtin_amdgcn_global_load_lds(
                (const __attribute__((address_space(1))) void*)(Wb + (size_t)rr[p] * K_TOT + kt + cc_[p] * 8),
                (__attribute__((address_space(3))) void*)(&Ws[buf][jj[p] * 8]),
                16, 0, 0);
    };

    stage(0, 0);
    __syncthreads();   // drains tile 0 AND the 12 pointwise loads together

    int cur = 0;
    for (int it = 0; it < NITER; ++it) {
        if (it + 1 < NITER) stage(cur ^ 1, (it + 1) * BK);

        #pragma unroll
        for (int ks = 0; ks < 2; ++ks) {
            const int cc = ks * 4 + lq;
            bfrag af[2], wf[2];
            #pragma unroll
            for (int t = 0; t < 2; ++t) {
                const int row = wm + t * 16 + lr;
                af[t] = *(const bfrag*)&As[cur][row * BK + ((cc ^ (row & 7)) << 3)];
            }
            #pragma unroll
            for (int t = 0; t < 2; ++t) {
                const int row = wn + t * 16 + lr;
                wf[t] = *(const bfrag*)&Ws[cur][row * BK + ((cc ^ (row & 7)) << 3)];
            }
            #pragma unroll
            for (int tm = 0; tm < 2; ++tm)
                #pragma unroll
                for (int tn = 0; tn < 2; ++tn)
                    acc[tm][tn] = __builtin_amdgcn_mfma_f32_16x16x32_bf16(
                        af[tm], wf[tn], acc[tm][tn], 0, 0, 0);
        }

        __syncthreads();   // vmcnt(0)+barrier: drains tile t+1, after compute
        cur ^= 1;
    }

    // ---- write-late pointwise planes (z, v, b) from prefetched regs ----
    const size_t PL = (size_t)B_ROWS * OUT_F;
    #pragma unroll
    for (int k = 0; k < 4; ++k) {
        f4 z, vn, bn;
        #pragma unroll
        for (int c = 0; c < 4; ++c) {
            const float v_dec = vv[k][c] + 0.1f * (ii[k][c] - vv[k][c]);
            const float b_dec = bb[k][c] + 1.25e-06f * (1.0f - bb[k][c]);
            const float zz = (v_dec - b_dec > 0.0f) ? 1.0f : 0.0f;
            z[c]  = zz;
            vn[c] = (1.0f - zz) * v_dec;
            bn[c] = b_dec + zz * 0.00225f;
        }
        const int j = pw + k * 256;
        __builtin_nontemporal_store(z,  (f4*)out + j);               // plane 0
        __builtin_nontemporal_store(vn, (f4*)(out + PL) + j);        // plane 1
        __builtin_nontemporal_store(bn, (f4*)(out + 3 * PL) + j);    // plane 3
    }

    // ---- epilogue: GEMM-dependent plane (i_new = i_decayed + acc) ----
    // C/D mapping col = lane&15, row = (lane>>4)*4 + reg (m89/m91).
    const size_t PL2 = 2 * PL;
    #pragma unroll
    for (int tm = 0; tm < 2; ++tm) {
        #pragma unroll
        for (int tn = 0; tn < 2; ++tn) {
            #pragma unroll
            for (int r = 0; r < 4; ++r) {
                const int gm = m0 + wm + tm * 16 + lq * 4 + r;
                const int gn = n0 + wn + tn * 16 + lr;
                const size_t idx = (size_t)gm * OUT_F + gn;
                const float i = iin[idx];
                __builtin_nontemporal_store((i - 0.2f * i) + acc[tm][tn][r],
                                            &out[PL2 + idx]);
            }
        }
    }
}

extern "C" void kernel_launch(void* const* d_in, const int* in_sizes, int n_in,
                              void* d_out, int out_size, void* d_ws, size_t ws_size,
                              hipStream_t stream) {
    const float* spikes = (const float*)d_in[0];
    const float* z      = (const float*)d_in[1];
    const float* v      = (const float*)d_in[2];
    const float* i      = (const float*)d_in[3];
    const float* b      = (const float*)d_in[4];
    const float* Wi     = (const float*)d_in[5];
    const float* Wr     = (const float*)d_in[6];
    float* out = (float*)d_out;

    unsigned short* Abf = (unsigned short*)d_ws;                       // 25,165,824 B
    unsigned short* Wbf = Abf + (size_t)B_ROWS * K_TOT;                //  3,145,728 B

    precast_aw<<<CAST_BLOCKS, 256, 0, stream>>>(spikes, z, Wi, Wr, Abf, Wbf);

    lsnn_gemm<<<GEMM_BLOCKS, 256, 0, stream>>>(Abf, Wbf, v, i, b, out);
}